// Round 1
// baseline (120.302 us; speedup 1.0000x reference)
//
#include <hip/hip_runtime.h>

// TContextGGANN_39805756899562
//
// The reference network is a fixed point at zero: all four hidden states
// (h_e, h_l, h_i, h_m) start at zero, every message is gated multiplicatively
// by a hidden state (enc_X * h_Y), the GRU maps (a=0, h=0) -> 0
// (r=z=0.5, h_tilde=tanh(0)=0, h'=(1-z)*0+z*0=0), and the final attention adds
// A@V with V built from zero states. The unused inputs (decay_mask_lower,
// time, lengths) never enter the computation. Hence the output
// (h_e,h_l,h_i,h_m flattened, 4*64*256*256 fp32 = 64 MB) is identically zero.
//
// Optimal kernel: a vectorized zero-fill of d_out (harness poisons d_out with
// 0xAA before every timed launch, so the write is mandatory every call).
// Write-bandwidth bound: 64 MB / ~6.3 TB/s ~= 10 us.

__global__ __launch_bounds__(256) void zero_fill_f4(float4* __restrict__ out,
                                                    int n4) {
    int i = blockIdx.x * blockDim.x + threadIdx.x;
    const float4 z = make_float4(0.f, 0.f, 0.f, 0.f);
    // grid-stride so any out_size works; with our launch config each thread
    // writes exactly one float4 (16 B/lane coalesced — the sweet spot).
    for (; i < n4; i += gridDim.x * blockDim.x) {
        out[i] = z;
    }
}

__global__ __launch_bounds__(256) void zero_fill_tail(float* __restrict__ out,
                                                      int start, int n) {
    int i = start + blockIdx.x * blockDim.x + threadIdx.x;
    if (i < n) out[i] = 0.f;
}

extern "C" void kernel_launch(void* const* d_in, const int* in_sizes, int n_in,
                              void* d_out, int out_size, void* d_ws, size_t ws_size,
                              hipStream_t stream) {
    (void)d_in; (void)in_sizes; (void)n_in; (void)d_ws; (void)ws_size;

    float* out = (float*)d_out;
    int n4 = out_size / 4;              // 16,777,216 / 4 = 4,194,304 float4s
    const int block = 256;
    int grid = (n4 + block - 1) / block;
    if (grid > 0) {
        zero_fill_f4<<<grid, block, 0, stream>>>((float4*)out, n4);
    }
    int tail_start = n4 * 4;
    int tail = out_size - tail_start;   // 0 for this problem, kept for safety
    if (tail > 0) {
        zero_fill_tail<<<1, block, 0, stream>>>(out, tail_start, out_size);
    }
}